// Round 3
// baseline (765.755 us; speedup 1.0000x reference)
//
#include <hip/hip_runtime.h>

#define GAMMA 0.01f
#define INV_GAMMA 100.0f
#define B 32
#define G 2048
#define C 16
#define S 8
#define L 3
#define M 16
#define NB 512          // blocks: 32 b x 16 half-tiles
#define HT 128          // g per block
#define POISON 0xAAAAAAAAu   // harness pre-poisons d_ws; all posted maxes are >=0 (sign bit 0)

__device__ __forceinline__ float waveMax(float v) {
#pragma unroll
    for (int off = 32; off > 0; off >>= 1)
        v = fmaxf(v, __shfl_xor(v, off, 64));
    return v;
}

// Block-wide max broadcast (256 threads). Leading guard sync makes repeated use safe.
__device__ __forceinline__ float blockMaxBcast(float v, float* scratch) {
    float wm = waveMax(v);
    __syncthreads();
    if ((threadIdx.x & 63) == 0) scratch[threadIdx.x >> 6] = wm;
    __syncthreads();
    return fmaxf(fmaxf(scratch[0], scratch[1]), fmaxf(scratch[2], scratch[3]));
}

// Wait until all n slots are posted (!= POISON), return softor scale 1/max (or 1).
// Agent-scope relaxed polls (bypass stale per-XCD caches) + one fence for data acquire.
__device__ __forceinline__ float pollMaxScale(const unsigned* slots, int n, float* scratch) {
    float v = -INFINITY;
    for (int j = threadIdx.x; j < n; j += 256) {
        unsigned u = __hip_atomic_load(&slots[j], __ATOMIC_RELAXED, __HIP_MEMORY_SCOPE_AGENT);
        while (u == POISON) {
            __builtin_amdgcn_s_sleep(1);
            u = __hip_atomic_load(&slots[j], __ATOMIC_RELAXED, __HIP_MEMORY_SCOPE_AGENT);
        }
        v = fmaxf(v, __uint_as_float(u));
    }
    __threadfence();   // acquire: make producers' global data (Ry) visible
    float m = blockMaxBcast(v, scratch);
    return (m > 1.0f) ? 1.0f / m : 1.0f;
}

__device__ __forceinline__ void postMax(unsigned* slot, float bm, bool fence) {
    if (threadIdx.x == 0) {
        if (fence) __threadfence();   // flush prior global stores (block's stores drained
                                      // to local L2 by blockMaxBcast's __syncthreads)
        __hip_atomic_store(slot, __float_as_uint(bm), __ATOMIC_RELEASE, __HIP_MEMORY_SCOPE_AGENT);
    }
}

__global__ __launch_bounds__(256, 2) void fused(
    const float* __restrict__ x, const float* __restrict__ W,
    const int* __restrict__ I, float* __restrict__ out,
    unsigned* __restrict__ SA, unsigned* __restrict__ SB,
    unsigned* __restrict__ SC, float* __restrict__ Ry) {
    __shared__ float Vrow[G];        // 8 KB: row b of V, pre-scaled
    __shared__ float CvL[C][HT];     // 8 KB: this block's Cv tile (never leaves LDS)
    __shared__ float WsL[M * C];     // 1 KB
    __shared__ float scratch[4];

    const int t   = threadIdx.x;
    const int blk = blockIdx.x;
    const int b   = blk >> 4;
    const int g0  = (blk & 15) * HT;

    // Ws = softmax(W, axis=1), redundantly per block (tiny)
    {
        int m = t >> 4, c = t & 15;
        float rmax = -INFINITY;
#pragma unroll
        for (int j = 0; j < C; j++) rmax = fmaxf(rmax, W[m * C + j]);
        float rsum = 0.f;
#pragma unroll
        for (int j = 0; j < C; j++) rsum += __expf(W[m * C + j] - rmax);
        WsL[t] = __expf(W[m * C + c] - rmax) / rsum;
        // first read of WsL is after several __syncthreads (inside blockMaxBcast)
    }

    // R carried in registers (unscaled y); scale s3 applied at consumption
    float Rreg = (t < HT) ? x[(size_t)b * G + g0 + t] : 0.f;
    float s3 = 1.0f;
    const float* Vsrc = x;

    for (int it = 0; it < 5; ++it) {
        // ---------- Phase A: Cv tile = softor_S(prod_L gather(V)) ----------
        {
            const float4* V4 = (const float4*)(Vsrc + (size_t)b * G);
            float4* Vr4 = (float4*)Vrow;
#pragma unroll
            for (int j = 0; j < 2; j++) {
                float4 v = V4[t + j * 256];
                v.x *= s3; v.y *= s3; v.z *= s3; v.w *= s3;
                Vr4[t + j * 256] = v;
            }
        }
        __syncthreads();

        const int gl = t & 127;
        const int cb = (t >> 7) * 8;           // threads split the 16 c's in halves
        float ymax = -INFINITY;
#pragma unroll 2
        for (int cc = 0; cc < 8; cc++) {
            const int c = cb + cc;
            const int4* ip = (const int4*)(I + ((size_t)c * G + g0 + gl) * (S * L));
            int idx[S * L];
#pragma unroll
            for (int q = 0; q < 6; q++) {
                int4 v = ip[q];
                idx[q * 4 + 0] = v.x; idx[q * 4 + 1] = v.y;
                idx[q * 4 + 2] = v.z; idx[q * 4 + 3] = v.w;
            }
            float body[S];
#pragma unroll
            for (int ss = 0; ss < S; ss++)
                body[ss] = Vrow[idx[ss * 3]] * Vrow[idx[ss * 3 + 1]] * Vrow[idx[ss * 3 + 2]];
            float bm = body[0];
#pragma unroll
            for (int ss = 1; ss < S; ss++) bm = fmaxf(bm, body[ss]);
            float sum = 0.f;
#pragma unroll
            for (int ss = 0; ss < S; ss++) sum += __expf((body[ss] - bm) * INV_GAMMA);
            float y = bm + GAMMA * __logf(sum);
            CvL[c][gl] = y;
            ymax = fmaxf(ymax, y);
        }
        float bmA = blockMaxBcast(ymax, scratch);   // syncs CvL for phase B too
        postMax(&SA[it * NB + blk], bmA, false);    // LDS-only data -> no fence
        float s1 = pollMaxScale(&SA[it * NB], NB, scratch);

        // ---------- Phase B: Hy = softor_M(Ws @ (s1*Cv)) ----------
        float hy = -INFINITY;
        if (t < HT) {
            float cv[C];
#pragma unroll
            for (int c = 0; c < C; c++) cv[c] = s1 * CvL[c][t];
            float hm = -INFINITY;
            float h[M];
#pragma unroll
            for (int m = 0; m < M; m++) {
                float acc = 0.f;
#pragma unroll
                for (int c = 0; c < C; c++) acc = fmaf(WsL[m * C + c], cv[c], acc);
                h[m] = acc; hm = fmaxf(hm, acc);
            }
            float sum = 0.f;
#pragma unroll
            for (int m = 0; m < M; m++) sum += __expf((h[m] - hm) * INV_GAMMA);
            hy = hm + GAMMA * __logf(sum);
        }
        float bmB = blockMaxBcast(hy, scratch);
        postMax(&SB[it * NB + blk], bmB, false);    // hy travels in registers -> no fence
        float s2 = pollMaxScale(&SB[it * NB], NB, scratch);

        // ---------- Phase C: R_new = softor_2(s3*R, s2*Hy) ----------
        float ynew = -INFINITY;
        if (t < HT) {
            float Rv = s3 * Rreg;
            float rv = s2 * hy;
            float a = fmaxf(Rv, rv), d = fminf(Rv, rv);
            ynew = a + GAMMA * __logf(1.0f + __expf((d - a) * INV_GAMMA));
            Rreg = ynew;
            if (it < 4) Ry[(size_t)b * G + g0 + t] = ynew;  // next iter's V
        }
        float bmC = blockMaxBcast(ynew, scratch);
        postMax(&SC[it * NB + blk], bmC, it < 4);   // fence: Ry must be visible
        s3 = pollMaxScale(&SC[it * NB], NB, scratch);
        Vsrc = Ry;
    }

    // ---------- Output: out = s3_final * R ----------
    if (t < HT) out[(size_t)b * G + g0 + t] = s3 * Rreg;
}

extern "C" void kernel_launch(void* const* d_in, const int* in_sizes, int n_in,
                              void* d_out, int out_size, void* d_ws, size_t ws_size,
                              hipStream_t stream) {
    const float* x = (const float*)d_in[0];   // (B,G)
    const float* W = (const float*)d_in[1];   // (M,C)
    const int*   I = (const int*)d_in[2];     // (C,G,S,L)
    float* out = (float*)d_out;

    unsigned* ws = (unsigned*)d_ws;
    unsigned* SA = ws;                        // 5*512 slots (poisoned 0xAA by harness)
    unsigned* SB = SA + 5 * NB;
    unsigned* SC = SB + 5 * NB;
    float*    Ry = (float*)(SC + 5 * NB);     // B*G

    void* args[] = { (void*)&x, (void*)&W, (void*)&I, (void*)&out,
                     (void*)&SA, (void*)&SB, (void*)&SC, (void*)&Ry };
    hipLaunchCooperativeKernel((const void*)fused, dim3(NB), dim3(256), args, 0, stream);
}

// Round 4
// 182.336 us; speedup vs baseline: 4.1997x; 4.1997x over previous
//
#include <hip/hip_runtime.h>

#define GAMMA 0.01f
#define INV_GAMMA 100.0f
#define B 32
#define G 2048
#define C 16
#define S 8
#define L 3
#define M 16
#define NB 256          // 32 b x 8 tiles
#define TPB 512
#define TILE 256        // g per block
#define POISON 0xAAAAAAAAu   // harness poisons d_ws; posted maxes are >=0 (sign bit 0)

__device__ __forceinline__ float waveMax(float v) {
#pragma unroll
    for (int off = 32; off > 0; off >>= 1)
        v = fmaxf(v, __shfl_xor(v, off, 64));
    return v;
}

// 512-thread block max, broadcast to all threads. Leading guard sync.
__device__ __forceinline__ float blockMaxBcast(float v, float* scratch8) {
    float wm = waveMax(v);
    __syncthreads();
    if ((threadIdx.x & 63) == 0) scratch8[threadIdx.x >> 6] = wm;
    __syncthreads();
    float r = scratch8[0];
#pragma unroll
    for (int i = 1; i < 8; i++) r = fmaxf(r, scratch8[i]);
    return r;
}

// Grid max for event e. bm must be block-reduced already (so a __syncthreads
// separates the previous read of *bcast from this call's write).
// Block 0 reduces the 256 slots; everyone else polls ONE result word.
__device__ __forceinline__ float gridMax(float bm, int e,
                                         unsigned* __restrict__ Slots,
                                         unsigned* __restrict__ Result,
                                         float* scratch8, float* bcast) {
    const int t = threadIdx.x;
    unsigned* slots = Slots + e * NB;
    if (t == 0)
        __hip_atomic_store(&slots[blockIdx.x], __float_as_uint(bm),
                           __ATOMIC_RELEASE, __HIP_MEMORY_SCOPE_AGENT);
    if (blockIdx.x == 0) {
        float v = -INFINITY;
        if (t < NB) {
            unsigned u = __hip_atomic_load(&slots[t], __ATOMIC_RELAXED,
                                           __HIP_MEMORY_SCOPE_AGENT);
            while (u == POISON) {
                __builtin_amdgcn_s_sleep(1);
                u = __hip_atomic_load(&slots[t], __ATOMIC_RELAXED,
                                      __HIP_MEMORY_SCOPE_AGENT);
            }
            v = __uint_as_float(u);
        }
        float gm = blockMaxBcast(v, scratch8);
        if (t == 0)
            __hip_atomic_store(&Result[e], __float_as_uint(gm),
                               __ATOMIC_RELEASE, __HIP_MEMORY_SCOPE_AGENT);
    }
    if (t == 0) {
        unsigned u = __hip_atomic_load(&Result[e], __ATOMIC_RELAXED,
                                       __HIP_MEMORY_SCOPE_AGENT);
        while (u == POISON) {
            __builtin_amdgcn_s_sleep(1);
            u = __hip_atomic_load(&Result[e], __ATOMIC_RELAXED,
                                  __HIP_MEMORY_SCOPE_AGENT);
        }
        *bcast = __uint_as_float(u);
    }
    __syncthreads();
    return *bcast;
}

__global__ __launch_bounds__(TPB, 1) void fused(
    const float* __restrict__ x, const float* __restrict__ W,
    const int* __restrict__ I, float* __restrict__ out,
    unsigned* __restrict__ Slots, unsigned* __restrict__ Result,
    float* __restrict__ Ry) {
    __shared__ float Vrow[G];        // 8 KB, row b of V (pre-scaled)
    __shared__ float CvL[C][TILE];   // 16 KB, block's Cv tile (LDS-only)
    __shared__ float WsL[M * C];     // 1 KB
    __shared__ float scratch8[8];
    __shared__ float bcast;

    const int t   = threadIdx.x;
    const int blk = blockIdx.x;
    const int b   = blk >> 3;
    const int g0  = (blk & 7) * TILE;

    // Ws = softmax(W, axis=1), redundantly per block (tiny). First read is
    // after phase A's blockMaxBcast syncs.
    if (t < M * C) {
        int m = t >> 4, c = t & 15;
        float rmax = -INFINITY;
#pragma unroll
        for (int j = 0; j < C; j++) rmax = fmaxf(rmax, W[m * C + j]);
        float rsum = 0.f;
#pragma unroll
        for (int j = 0; j < C; j++) rsum += __expf(W[m * C + j] - rmax);
        WsL[t] = __expf(W[m * C + c] - rmax) / rsum;
    }

    float Rreg = (t < TILE) ? x[(size_t)b * G + g0 + t] : 0.f;  // unscaled y
    float s3 = 1.0f;

    for (int it = 0; it < 5; ++it) {
        // ---- stage V row b into LDS (scaled by s3) ----
        if (it == 0) {
            float4 v = ((const float4*)(x + (size_t)b * G))[t];  // 512*16B = 8KB
            ((float4*)Vrow)[t] = v;                              // s3 == 1
        } else {
            // agent loads: bypass stale per-XCD L2; producers stored agent-scope
#pragma unroll
            for (int k = 0; k < 4; k++) {
                int j = t + k * TPB;
                float v = __hip_atomic_load(&Ry[(size_t)b * G + j],
                                            __ATOMIC_RELAXED, __HIP_MEMORY_SCOPE_AGENT);
                Vrow[j] = s3 * v;
            }
        }
        __syncthreads();

        // ---- Phase A: Cv tile = softor_S(prod_L gather(V)) ----
        const int gl = t & 255;
        const int cb = (t >> 8) * 8;
        float ymax = -INFINITY;
#pragma unroll 2
        for (int cc = 0; cc < 8; cc++) {
            const int c = cb + cc;
            const int4* ip = (const int4*)(I + ((size_t)c * G + g0 + gl) * (S * L));
            int idx[S * L];
#pragma unroll
            for (int q = 0; q < 6; q++) {
                int4 v = ip[q];
                idx[q * 4 + 0] = v.x; idx[q * 4 + 1] = v.y;
                idx[q * 4 + 2] = v.z; idx[q * 4 + 3] = v.w;
            }
            float body[S];
#pragma unroll
            for (int ss = 0; ss < S; ss++)
                body[ss] = Vrow[idx[ss * 3]] * Vrow[idx[ss * 3 + 1]] * Vrow[idx[ss * 3 + 2]];
            float bm = body[0];
#pragma unroll
            for (int ss = 1; ss < S; ss++) bm = fmaxf(bm, body[ss]);
            float sum = 0.f;
#pragma unroll
            for (int ss = 0; ss < S; ss++) sum += __expf((body[ss] - bm) * INV_GAMMA);
            float y = bm + GAMMA * __logf(sum);
            CvL[c][gl] = y;
            ymax = fmaxf(ymax, y);
        }
        float bmA = blockMaxBcast(ymax, scratch8);   // also publishes CvL block-wide
        float m1 = gridMax(bmA, it * 3 + 0, Slots, Result, scratch8, &bcast);
        float s1 = (m1 > 1.0f) ? 1.0f / m1 : 1.0f;

        // ---- Phase B: Hy = softor_M(Ws @ (s1*Cv)) ----
        float hy = -INFINITY;
        if (t < TILE) {
            float cv[C];
#pragma unroll
            for (int c = 0; c < C; c++) cv[c] = s1 * CvL[c][t];
            float hm = -INFINITY;
            float h[M];
#pragma unroll
            for (int m = 0; m < M; m++) {
                float acc = 0.f;
#pragma unroll
                for (int c = 0; c < C; c++) acc = fmaf(WsL[m * C + c], cv[c], acc);
                h[m] = acc; hm = fmaxf(hm, acc);
            }
            float sum = 0.f;
#pragma unroll
            for (int m = 0; m < M; m++) sum += __expf((h[m] - hm) * INV_GAMMA);
            hy = hm + GAMMA * __logf(sum);
        }
        float bmB = blockMaxBcast(hy, scratch8);
        float m2 = gridMax(bmB, it * 3 + 1, Slots, Result, scratch8, &bcast);
        float s2 = (m2 > 1.0f) ? 1.0f / m2 : 1.0f;

        // ---- Phase C: R_new = softor_2(s3*R, s2*Hy) ----
        float ynew = -INFINITY;
        if (t < TILE) {
            float Rv = s3 * Rreg;
            float rv = s2 * hy;
            float a = fmaxf(Rv, rv), d = fminf(Rv, rv);
            ynew = a + GAMMA * __logf(1.0f + __expf((d - a) * INV_GAMMA));
            Rreg = ynew;
            if (it < 4)   // agent store -> LLC; drained by vmcnt(0) at the
                          // __syncthreads inside blockMaxBcast, before slot post
                __hip_atomic_store(&Ry[(size_t)b * G + g0 + t], ynew,
                                   __ATOMIC_RELAXED, __HIP_MEMORY_SCOPE_AGENT);
        }
        float bmC = blockMaxBcast(ynew, scratch8);
        float m3 = gridMax(bmC, it * 3 + 2, Slots, Result, scratch8, &bcast);
        s3 = (m3 > 1.0f) ? 1.0f / m3 : 1.0f;
    }

    if (t < TILE) out[(size_t)b * G + g0 + t] = s3 * Rreg;
}

extern "C" void kernel_launch(void* const* d_in, const int* in_sizes, int n_in,
                              void* d_out, int out_size, void* d_ws, size_t ws_size,
                              hipStream_t stream) {
    const float* x = (const float*)d_in[0];   // (B,G)
    const float* W = (const float*)d_in[1];   // (M,C)
    const int*   I = (const int*)d_in[2];     // (C,G,S,L)
    float* out = (float*)d_out;

    unsigned* ws     = (unsigned*)d_ws;
    unsigned* Slots  = ws;                    // 15 * 256 (poisoned 0xAA)
    unsigned* Result = ws + 15 * NB;          // 15 (poisoned 0xAA)
    float*    Ry     = (float*)(ws + 15 * NB + 32);  // B*G

    void* args[] = { (void*)&x, (void*)&W, (void*)&I, (void*)&out,
                     (void*)&Slots, (void*)&Result, (void*)&Ry };
    hipLaunchCooperativeKernel((const void*)fused, dim3(NB), dim3(TPB), args, 0, stream);
}